// Round 20
// baseline (281.499 us; speedup 1.0000x reference)
//
#include <hip/hip_runtime.h>
#include <hip/hip_fp16.h>

#define HIST 50
#define WPB 8   // waves per block (512 threads)

typedef __fp16 hf;
typedef __fp16 hf2 __attribute__((ext_vector_type(2)));
typedef __fp16 h8  __attribute__((ext_vector_type(8)));
typedef float  f4  __attribute__((ext_vector_type(4)));

union U32H2 { unsigned u; hf2 h; };
union U4H8  { uint4 u; h8 h; };
__device__ __forceinline__ unsigned h2u(hf2 h){ U32H2 c; c.h=h; return c.u; }
__device__ __forceinline__ hf2 pkrtz(float a,float b){ return __builtin_amdgcn_cvt_pkrtz(a,b); }

__device__ __forceinline__ h8 mk8(hf2 a, hf2 b, hf2 c, hf2 d){
    h8 r; r[0]=a[0]; r[1]=a[1]; r[2]=b[0]; r[3]=b[1]; r[4]=c[0]; r[5]=c[1]; r[6]=d[0]; r[7]=d[1]; return r;
}
// 8 consecutive f32 at W[row + kb .. +7] -> f16x8 fragment
__device__ __forceinline__ h8 ldfrag(const float* W, long row, int kb){
    const float4 v0 = *(const float4*)(W + row + kb);
    const float4 v1 = *(const float4*)(W + row + kb + 4);
    return mk8(pkrtz(v0.x,v0.y), pkrtz(v0.z,v0.w), pkrtz(v1.x,v1.y), pkrtz(v1.z,v1.w));
}
__device__ __forceinline__ f4 mfma16(h8 a, h8 b, f4 c){
    return __builtin_amdgcn_mfma_f32_16x16x32_f16(a,b,c,0,0,0);
}
__device__ __forceinline__ f4 relu4(f4 v){
    v[0]=fmaxf(v[0],0.f); v[1]=fmaxf(v[1],0.f); v[2]=fmaxf(v[2],0.f); v[3]=fmaxf(v[3],0.f); return v;
}
// intra-wave LDS write->read fence (rule #18)
__device__ __forceinline__ void wsync(){
    asm volatile("s_waitcnt lgkmcnt(0)" ::: "memory");
    __builtin_amdgcn_sched_barrier(0);
}

// C-layout (col=pair=nidx, feats rows 16nt+4kg+r) -> next layer's two B-frags (K=64),
// pure register shuffles: dest (nidx,kg) frag kt elem i = feat 32kt+8kg+i from lane
// nidx+16*((2kg+(i>=4))&3), slot nt=2kt+(kg>>1), r=i&3.
__device__ __forceinline__ void hop(const f4* v, int nidx, int kg, h8& B0, h8& B1){
    const unsigned p00 = h2u(pkrtz(v[0][0], v[0][1])), p01 = h2u(pkrtz(v[0][2], v[0][3]));
    const unsigned p10 = h2u(pkrtz(v[1][0], v[1][1])), p11 = h2u(pkrtz(v[1][2], v[1][3]));
    const unsigned p20 = h2u(pkrtz(v[2][0], v[2][1])), p21 = h2u(pkrtz(v[2][2], v[2][3]));
    const unsigned p30 = h2u(pkrtz(v[3][0], v[3][1])), p31 = h2u(pkrtz(v[3][2], v[3][3]));
    const int srcA = nidx + 16*(( 2*kg    ) & 3);
    const int srcB = nidx + 16*(( 2*kg + 1) & 3);
    const bool hi = (kg >= 2);
    unsigned a0,a1,b0,b1,c0,c1,d0,d1;
    // kt = 0: nt_s = hi ? 1 : 0
    a0=(unsigned)__shfl((int)p00,srcA); a1=(unsigned)__shfl((int)p01,srcA);
    b0=(unsigned)__shfl((int)p10,srcA); b1=(unsigned)__shfl((int)p11,srcA);
    c0=(unsigned)__shfl((int)p00,srcB); c1=(unsigned)__shfl((int)p01,srcB);
    d0=(unsigned)__shfl((int)p10,srcB); d1=(unsigned)__shfl((int)p11,srcB);
    { U4H8 t; t.u.x = hi?b0:a0; t.u.y = hi?b1:a1; t.u.z = hi?d0:c0; t.u.w = hi?d1:c1; B0 = t.h; }
    // kt = 1: nt_s = hi ? 3 : 2
    a0=(unsigned)__shfl((int)p20,srcA); a1=(unsigned)__shfl((int)p21,srcA);
    b0=(unsigned)__shfl((int)p30,srcA); b1=(unsigned)__shfl((int)p31,srcA);
    c0=(unsigned)__shfl((int)p20,srcB); c1=(unsigned)__shfl((int)p21,srcB);
    d0=(unsigned)__shfl((int)p30,srcB); d1=(unsigned)__shfl((int)p31,srcB);
    { U4H8 t; t.u.x = hi?b0:a0; t.u.y = hi?b1:a1; t.u.z = hi?d0:c0; t.u.w = hi?d1:c1; B1 = t.h; }
}

__global__ __launch_bounds__(512, 2)   // verified no-spill operating point
void ue_v6(const int* __restrict__ nodes, const int* __restrict__ hitems,
           const int* __restrict__ hrat, const int* __restrict__ hlen,
           const float* __restrict__ u2e, const float* __restrict__ i2e,
           const float* __restrict__ r2e,
           const float* __restrict__ w1w, const float* __restrict__ w1b,
           const float* __restrict__ w2w, const float* __restrict__ w2b,
           const float* __restrict__ a1w, const float* __restrict__ a1b,
           const float* __restrict__ a2w, const float* __restrict__ a2b,
           const float* __restrict__ a3w, const float* __restrict__ a3b,
           float* __restrict__ out, int n_nodes)
{
    const int tid  = threadIdx.x;
    const int lane = tid & 63;
    const int wid  = tid >> 6;
    const int nidx = lane & 15;
    const int kg   = lane >> 4;

    // weight fragments (same layout as verified R16; now used as MFMA-A operands)
    __shared__ __align__(16) unsigned short wlds[40*512];
    __shared__ __align__(16) float bt[4*64];           // w1b | w2b | a2b | a3w
    __shared__ __align__(16) float uax[WPB][64];
    __shared__ __align__(16) float ubl[WPB][64];
    __shared__ int ihs[WPB][HIST];
    __shared__ int rhs[WPB][HIST];

    for (int f = tid; f < 40*64; f += blockDim.x) {
        const int blk = f >> 6, l = f & 63;
        const float* src; int ld, kt, nt;
        if (blk < 16)      { kt = blk>>2;      nt = blk&3;      src = w1w; ld = 128; }
        else if (blk < 24) { kt = (blk-16)>>2; nt = (blk-16)&3; src = w2w; ld = 64;  }
        else if (blk < 32) { kt = (blk-24)>>2; nt = (blk-24)&3; src = a1w; ld = 128; }
        else               { kt = (blk-32)>>2; nt = (blk-32)&3; src = a2w; ld = 64;  }
        const int nrow = 16*nt + (l & 15);
        const int kcol = 32*kt + 8*(l >> 4);
        *(h8*)&wlds[blk*512 + l*8] = ldfrag(src, (long)nrow*ld, kcol);
    }
    if (tid < 256) {
        const int m = tid >> 6, j = tid & 63;
        const float* s = (m==0) ? w1b : (m==1) ? w2b : (m==2) ? a2b : a3w;
        bt[m*64 + j] = s[j];
    }
    __syncthreads();   // the ONLY block-wide barrier

    #define AF(base,kt,nt) (*(const h8*)&wlds[((base)+(kt)*4+(nt))*512 + lane*8])
    const int bofs = 16*0 + 0;   // silence unused warnings pattern
    (void)bofs;
    const float NEG_INF = -__builtin_inff();
    const float ab1r = a1b[lane];

    for (int n = blockIdx.x * WPB + wid; n < n_nodes; n += gridDim.x * WPB) {
        const int node = nodes[n];
        const int hl   = hlen[n];

        uax[wid][lane] = u2e[(long)node * 64 + lane];
        if (lane < HIST){ ihs[wid][lane] = hitems[n*HIST+lane]; rhs[wid][lane] = hrat[n*HIST+lane]; }
        wsync();

        // ubias_j = ab1_j + sum_k u_k * A1[j][64+k]  (u-half of att1, folded per node)
        float u0 = ab1r, u1 = 0.f, u2 = 0.f, u3 = 0.f;
        #pragma unroll
        for (int t = 0; t < 16; ++t) {
            const float4 v = *(const float4*)(a1w + (long)lane*128 + 64 + 4*t);
            u0 = fmaf(v.x, uax[wid][4*t+0], u0);
            u1 = fmaf(v.y, uax[wid][4*t+1], u1);
            u2 = fmaf(v.z, uax[wid][4*t+2], u2);
            u3 = fmaf(v.w, uax[wid][4*t+3], u3);
        }
        ubl[wid][lane] = (u0 + u1) + (u2 + u3);
        wsync();

        float m_run = NEG_INF, run_sum = 0.f;
        f4 outacc[4];
        #pragma unroll
        for (int nt = 0; nt < 4; ++nt) outacc[nt] = (f4){0.f,0.f,0.f,0.f};

        const int tiles = (hl + 15) >> 4;
        for (int t = 0; t < tiles; ++t) {
            int p = t*16 + nidx; if (p >= hl) p = hl - 1;   // clamp pad pairs (masked below)
            const long irow = (long)ihs[wid][p] * 64;
            const long rrow = (long)rhs[wid][p] * 64;
            const int  kb   = 8 * kg;
            // X as B-operand fragments (pair = nidx, k = feat)
            const h8 Xf0 = ldfrag(i2e, irow, kb);
            const h8 Xf1 = ldfrag(i2e, irow, 32 + kb);
            const h8 Xf2 = ldfrag(r2e, rrow, kb);
            const h8 Xf3 = ldfrag(r2e, rrow, 32 + kb);

            // ---- layer 1: D = W1·X^T  (rows=out-feat, cols=pair) ----
            f4 acc[4];
            #pragma unroll
            for (int nt = 0; nt < 4; ++nt){
                f4 c = *(const f4*)&bt[0*64 + 16*nt + 4*kg];
                c = mfma16(AF(0,0,nt), Xf0, c);
                c = mfma16(AF(0,1,nt), Xf1, c);
                c = mfma16(AF(0,2,nt), Xf2, c);
                c = mfma16(AF(0,3,nt), Xf3, c);
                acc[nt] = relu4(c);
            }
            h8 Bf0, Bf1;
            hop(acc, nidx, kg, Bf0, Bf1);     // y -> B-frags, register-only

            // ---- layer 2: o = W2·y ----
            f4 occ[4];
            #pragma unroll
            for (int nt = 0; nt < 4; ++nt){
                f4 c = *(const f4*)&bt[1*64 + 16*nt + 4*kg];
                c = mfma16(AF(16,0,nt), Bf0, c);
                c = mfma16(AF(16,1,nt), Bf1, c);
                occ[nt] = relu4(c);
            }
            hop(occ, nidx, kg, Bf0, Bf1);     // o -> B-frags

            // ---- att layer 1 (o-half; u folded into ubias) ----
            #pragma unroll
            for (int nt = 0; nt < 4; ++nt){
                f4 c = *(const f4*)&ubl[wid][16*nt + 4*kg];
                c = mfma16(AF(24,0,nt), Bf0, c);
                c = mfma16(AF(24,1,nt), Bf1, c);
                acc[nt] = relu4(c);
            }
            hop(acc, nidx, kg, Bf0, Bf1);     // a1 -> B-frags

            // ---- att layer 2 ----
            #pragma unroll
            for (int nt = 0; nt < 4; ++nt){
                f4 c = *(const f4*)&bt[2*64 + 16*nt + 4*kg];
                c = mfma16(AF(32,0,nt), Bf0, c);
                c = mfma16(AF(32,1,nt), Bf1, c);
                acc[nt] = relu4(c);
            }

            // ---- score_p = sum_f a3[f]*av2[f][p]  (att3 bias dropped: shift-invariant) ----
            float sv = 0.f;
            #pragma unroll
            for (int nt = 0; nt < 4; ++nt){
                const f4 a3v = *(const f4*)&bt[3*64 + 16*nt + 4*kg];
                sv = fmaf(a3v[0], acc[nt][0], sv);
                sv = fmaf(a3v[1], acc[nt][1], sv);
                sv = fmaf(a3v[2], acc[nt][2], sv);
                sv = fmaf(a3v[3], acc[nt][3], sv);
            }
            sv += __shfl_xor(sv, 16);
            sv += __shfl_xor(sv, 32);          // full score for pair nidx, all kg copies

            // ---- online softmax update (own pair = nidx) ----
            const bool valid = (t*16 + nidx) < hl;
            float tmax = valid ? sv : NEG_INF;
            tmax = fmaxf(tmax, __shfl_xor(tmax, 1));
            tmax = fmaxf(tmax, __shfl_xor(tmax, 2));
            tmax = fmaxf(tmax, __shfl_xor(tmax, 4));
            tmax = fmaxf(tmax, __shfl_xor(tmax, 8));
            const float m_new = fmaxf(m_run, tmax);
            const float fs = expf(m_run - m_new);   // 0 on first tile
            const float w = valid ? expf(sv - m_new) : 0.f;
            float wsum = w;
            wsum += __shfl_xor(wsum, 1);
            wsum += __shfl_xor(wsum, 2);
            wsum += __shfl_xor(wsum, 4);
            wsum += __shfl_xor(wsum, 8);
            run_sum = run_sum * fs + wsum;
            #pragma unroll
            for (int nt = 0; nt < 4; ++nt){
                f4 o = occ[nt];
                o[0] *= w; o[1] *= w; o[2] *= w; o[3] *= w;
                f4 oa = outacc[nt];
                oa[0] = oa[0]*fs + o[0];
                oa[1] = oa[1]*fs + o[1];
                oa[2] = oa[2]*fs + o[2];
                oa[3] = oa[3]*fs + o[3];
                outacc[nt] = oa;
            }
            m_run = m_new;
        }

        // ---- reduce outacc over pairs (nidx lanes) and write ----
        #pragma unroll
        for (int nt = 0; nt < 4; ++nt){
            f4 oa = outacc[nt];
            #pragma unroll
            for (int r = 0; r < 4; ++r){
                oa[r] += __shfl_xor(oa[r], 1);
                oa[r] += __shfl_xor(oa[r], 2);
                oa[r] += __shfl_xor(oa[r], 4);
                oa[r] += __shfl_xor(oa[r], 8);
            }
            outacc[nt] = oa;
        }
        const float inv = 1.f / run_sum;
        if (nidx == 0){
            #pragma unroll
            for (int nt = 0; nt < 4; ++nt){
                out[(long)n*64 + 16*nt + 4*kg + 0] = outacc[nt][0] * inv;
                out[(long)n*64 + 16*nt + 4*kg + 1] = outacc[nt][1] * inv;
                out[(long)n*64 + 16*nt + 4*kg + 2] = outacc[nt][2] * inv;
                out[(long)n*64 + 16*nt + 4*kg + 3] = outacc[nt][3] * inv;
            }
        }
    }
    #undef AF
}

extern "C" void kernel_launch(void* const* d_in, const int* in_sizes, int n_in,
                              void* d_out, int out_size, void* d_ws, size_t ws_size,
                              hipStream_t stream) {
    const int*   nodes  = (const int*)d_in[0];
    const int*   hitems = (const int*)d_in[1];
    const int*   hrat   = (const int*)d_in[2];
    const int*   hlenp  = (const int*)d_in[3];
    const float* u2e    = (const float*)d_in[4];
    const float* i2e    = (const float*)d_in[5];
    const float* r2e    = (const float*)d_in[6];
    const float* w1w    = (const float*)d_in[7];
    const float* w1b    = (const float*)d_in[8];
    const float* w2w    = (const float*)d_in[9];
    const float* w2b    = (const float*)d_in[10];
    const float* a1w    = (const float*)d_in[11];
    const float* a1b    = (const float*)d_in[12];
    const float* a2w    = (const float*)d_in[13];
    const float* a2b    = (const float*)d_in[14];
    const float* a3w    = (const float*)d_in[15];
    const float* a3b    = (const float*)d_in[16];
    float* out = (float*)d_out;

    const int n_nodes = in_sizes[0];
    const int blocks  = 2048;   // 8 waves each: one node per wave
    ue_v6<<<dim3(blocks), dim3(512), 0, stream>>>(
        nodes, hitems, hrat, hlenp, u2e, i2e, r2e,
        w1w, w1b, w2w, w2b, a1w, a1b, a2w, a2b, a3w, a3b,
        out, n_nodes);
}

// Round 21
// 144.686 us; speedup vs baseline: 1.9456x; 1.9456x over previous
//
#include <hip/hip_runtime.h>
#include <hip/hip_fp16.h>

#define HIST 50
#define WPB 8   // waves per block (512 threads)

typedef __fp16 hf;
typedef __fp16 hf2 __attribute__((ext_vector_type(2)));
typedef __fp16 h8  __attribute__((ext_vector_type(8)));
typedef float  f4  __attribute__((ext_vector_type(4)));

union U32H2 { unsigned u; hf2 h; };
__device__ __forceinline__ unsigned h2u(hf2 h){ U32H2 c; c.h=h; return c.u; }
__device__ __forceinline__ hf2 pkrtz(float a,float b){ return __builtin_amdgcn_cvt_pkrtz(a,b); }

__device__ __forceinline__ h8 mk8(hf2 a, hf2 b, hf2 c, hf2 d){
    h8 r; r[0]=a[0]; r[1]=a[1]; r[2]=b[0]; r[3]=b[1]; r[4]=c[0]; r[5]=c[1]; r[6]=d[0]; r[7]=d[1]; return r;
}
// 8 consecutive f32 at W[row + kb .. +7] -> f16x8 fragment
__device__ __forceinline__ h8 ldfrag(const float* W, long row, int kb){
    const float4 v0 = *(const float4*)(W + row + kb);
    const float4 v1 = *(const float4*)(W + row + kb + 4);
    return mk8(pkrtz(v0.x,v0.y), pkrtz(v0.z,v0.w), pkrtz(v1.x,v1.y), pkrtz(v1.z,v1.w));
}
__device__ __forceinline__ f4 mfma16(h8 a, h8 b, f4 c){
    return __builtin_amdgcn_mfma_f32_16x16x32_f16(a,b,c,0,0,0);
}
__device__ __forceinline__ f4 relu4(f4 v){
    v[0]=fmaxf(v[0],0.f); v[1]=fmaxf(v[1],0.f); v[2]=fmaxf(v[2],0.f); v[3]=fmaxf(v[3],0.f); return v;
}
// intra-wave LDS write->read fence (in-order DS pipe + stop compiler reordering; rule #18)
__device__ __forceinline__ void wsync(){
    asm volatile("s_waitcnt lgkmcnt(0)" ::: "memory");
    __builtin_amdgcn_sched_barrier(0);
}

// store C-layout tile (acc[nt]: col=16nt+(lane&15), rows (lane>>4)*4+r) as swizzled f16 [16][64]
__device__ __forceinline__ void store_ct(unsigned short* base, const f4* acc, int lane){
    const int m0    = (lane>>4)*4;
    const int ceven = lane & 14;
    const bool odd  = lane & 1;
    #pragma unroll
    for (int nt = 0; nt < 4; ++nt){
        const int c0 = 16*nt + ceven;
        #pragma unroll
        for (int r = 0; r < 4; ++r){
            const float mine = acc[nt][r];
            const float oth  = __shfl_xor(mine, 1);
            if (!odd){
                const int m    = m0 + r;
                const int gp   = (c0 >> 3) ^ (m & 7);
                const int byte = m*128 + gp*16 + ((2*c0) & 15);
                *(unsigned*)((char*)base + byte) = h2u(pkrtz(mine, oth));
            }
        }
    }
}
__device__ __forceinline__ h8 read_af(const unsigned short* base, int lane, int kt){
    const int row  = lane & 15;
    const int gp   = (4*kt + (lane>>4)) ^ (row & 7);
    const int byte = row*128 + gp*16;
    return *(const h8*)((const char*)base + byte);
}

__global__ __launch_bounds__(512, 2)   // verified no-spill operating point (VGPR ~108)
void ue_v7(const int* __restrict__ nodes, const int* __restrict__ hitems,
           const int* __restrict__ hrat, const int* __restrict__ hlen,
           const float* __restrict__ u2e, const float* __restrict__ i2e,
           const float* __restrict__ r2e,
           const float* __restrict__ w1w, const float* __restrict__ w1b,
           const float* __restrict__ w2w, const float* __restrict__ w2b,
           const float* __restrict__ a1w, const float* __restrict__ a1b,
           const float* __restrict__ a2w, const float* __restrict__ a2b,
           const float* __restrict__ a3w, const float* __restrict__ a3b,
           float* __restrict__ out, int n_nodes)
{
    const int tid  = threadIdx.x;
    const int lane = tid & 63;
    const int wid  = tid >> 6;
    const int nidx = lane & 15;
    const int kg   = lane >> 4;

    // weight fragments: 40 blocks (W1:0-15, W2:16-23, A1o:24-31, A2:32-39), each 64 lanes x 16B
    __shared__ __align__(16) unsigned short wlds[40*512];
    __shared__ __align__(16) unsigned short xfer[WPB][16*64];   // per-wave transpose buffer
    __shared__ __align__(16) float uax[WPB][64];
    __shared__ __align__(16) float ubl[WPB][64];
    __shared__ int ihs[WPB][HIST];
    __shared__ int rhs[WPB][HIST];

    // ---- cooperative weight staging (once per block; 512 blocks -> 4x amortized vs 2048) ----
    for (int f = tid; f < 40*64; f += blockDim.x) {
        const int blk = f >> 6, l = f & 63;
        const float* src; int ld, kt, nt;
        if (blk < 16)      { kt = blk>>2;      nt = blk&3;      src = w1w; ld = 128; }
        else if (blk < 24) { kt = (blk-16)>>2; nt = (blk-16)&3; src = w2w; ld = 64;  }
        else if (blk < 32) { kt = (blk-24)>>2; nt = (blk-24)&3; src = a1w; ld = 128; }
        else               { kt = (blk-32)>>2; nt = (blk-32)&3; src = a2w; ld = 64;  }
        const int nrow = 16*nt + (l & 15);
        const int kcol = 32*kt + 8*(l >> 4);
        *(h8*)&wlds[blk*512 + l*8] = ldfrag(src, (long)nrow*ld, kcol);
    }
    __syncthreads();   // the ONLY block-wide barrier

    #define BF(base,kt,nt) (*(const h8*)&wlds[((base)+(kt)*4+(nt))*512 + lane*8])

    float b1c[4], b2c[4], ab2c[4], a3c[4];
    #pragma unroll
    for (int nt = 0; nt < 4; ++nt){
        b1c[nt]  = w1b[16*nt + nidx];
        b2c[nt]  = w2b[16*nt + nidx];
        ab2c[nt] = a2b[16*nt + nidx];
        a3c[nt]  = a3w[16*nt + nidx];
    }
    const float ab1r = a1b[lane];
    const float NEG_INF = -__builtin_inff();

    // grid-stride: each wave handles 4 nodes (sum of 4 ragged hl -> better block balance)
    for (int n = blockIdx.x * WPB + wid; n < n_nodes; n += gridDim.x * WPB) {
        const int node = nodes[n];
        const int hl   = hlen[n];

        uax[wid][lane] = u2e[(long)node * 64 + lane];
        if (lane < HIST){ ihs[wid][lane] = hitems[n*HIST+lane]; rhs[wid][lane] = hrat[n*HIST+lane]; }
        wsync();

        // ubias_j = ab1_j + sum_k u_k * A1[j][64+k]  (u-half of att1, folded per node)
        float u0 = ab1r, u1 = 0.f, u2 = 0.f, u3 = 0.f;
        #pragma unroll
        for (int t = 0; t < 16; ++t) {
            const float4 v = *(const float4*)(a1w + (long)lane*128 + 64 + 4*t);
            u0 = fmaf(v.x, uax[wid][4*t+0], u0);
            u1 = fmaf(v.y, uax[wid][4*t+1], u1);
            u2 = fmaf(v.z, uax[wid][4*t+2], u2);
            u3 = fmaf(v.w, uax[wid][4*t+3], u3);
        }
        ubl[wid][lane] = (u0 + u1) + (u2 + u3);
        wsync();
        float ubc[4];
        #pragma unroll
        for (int nt = 0; nt < 4; ++nt) ubc[nt] = ubl[wid][16*nt + nidx];

        // online softmax state
        float m_run = NEG_INF, run_sum = 0.f;
        float outacc[4] = {0.f, 0.f, 0.f, 0.f};

        const int tiles = (hl + 15) >> 4;
        for (int t = 0; t < tiles; ++t) {
            int p = t*16 + nidx; if (p >= hl) p = hl - 1;   // clamp pad rows (masked below)
            const long irow = (long)ihs[wid][p] * 64;
            const long rrow = (long)rhs[wid][p] * 64;
            const int  kb   = 8 * kg;
            const h8 Xf0 = ldfrag(i2e, irow, kb);
            const h8 Xf1 = ldfrag(i2e, irow, 32 + kb);
            const h8 Xf2 = ldfrag(r2e, rrow, kb);
            const h8 Xf3 = ldfrag(r2e, rrow, 32 + kb);

            // layer 1: [16x128] @ [128x64]
            f4 acc[4];
            #pragma unroll
            for (int nt = 0; nt < 4; ++nt){
                f4 c = { b1c[nt], b1c[nt], b1c[nt], b1c[nt] };
                c = mfma16(Xf0, BF(0,0,nt), c);
                c = mfma16(Xf1, BF(0,1,nt), c);
                c = mfma16(Xf2, BF(0,2,nt), c);
                c = mfma16(Xf3, BF(0,3,nt), c);
                acc[nt] = relu4(c);
            }
            store_ct(xfer[wid], acc, lane);
            wsync();
            const h8 yf0 = read_af(xfer[wid], lane, 0), yf1 = read_af(xfer[wid], lane, 1);

            // layer 2 -> o (stays in f32 C-layout regs)
            f4 occ[4];
            #pragma unroll
            for (int nt = 0; nt < 4; ++nt){
                f4 c = { b2c[nt], b2c[nt], b2c[nt], b2c[nt] };
                c = mfma16(yf0, BF(16,0,nt), c);
                c = mfma16(yf1, BF(16,1,nt), c);
                occ[nt] = relu4(c);
            }
            store_ct(xfer[wid], occ, lane);
            wsync();
            const h8 of0 = read_af(xfer[wid], lane, 0), of1 = read_af(xfer[wid], lane, 1);

            // att layer 1 (o-half; u folded in ubias)
            #pragma unroll
            for (int nt = 0; nt < 4; ++nt){
                f4 c = { ubc[nt], ubc[nt], ubc[nt], ubc[nt] };
                c = mfma16(of0, BF(24,0,nt), c);
                c = mfma16(of1, BF(24,1,nt), c);
                acc[nt] = relu4(c);
            }
            store_ct(xfer[wid], acc, lane);
            wsync();
            const h8 af0 = read_af(xfer[wid], lane, 0), af1 = read_af(xfer[wid], lane, 1);

            // att layer 2
            #pragma unroll
            for (int nt = 0; nt < 4; ++nt){
                f4 c = { ab2c[nt], ab2c[nt], ab2c[nt], ab2c[nt] };
                c = mfma16(af0, BF(32,0,nt), c);
                c = mfma16(af1, BF(32,1,nt), c);
                acc[nt] = relu4(c);
            }

            // scores per row (att3 bias dropped: softmax shift-invariant)
            float sv0 = 0.f, sv1 = 0.f, sv2 = 0.f, sv3 = 0.f;
            #pragma unroll
            for (int nt = 0; nt < 4; ++nt){
                sv0 = fmaf(acc[nt][0], a3c[nt], sv0);
                sv1 = fmaf(acc[nt][1], a3c[nt], sv1);
                sv2 = fmaf(acc[nt][2], a3c[nt], sv2);
                sv3 = fmaf(acc[nt][3], a3c[nt], sv3);
            }
            #pragma unroll
            for (int off = 1; off <= 8; off <<= 1){
                sv0 += __shfl_xor(sv0, off);
                sv1 += __shfl_xor(sv1, off);
                sv2 += __shfl_xor(sv2, off);
                sv3 += __shfl_xor(sv3, off);
            }

            // online softmax update over this tile's 16 rows
            const int base = t*16 + kg*4;
            const bool v0 = base+0 < hl, v1 = base+1 < hl, v2 = base+2 < hl, v3 = base+3 < hl;
            float tmax = fmaxf(fmaxf(v0 ? sv0 : NEG_INF, v1 ? sv1 : NEG_INF),
                               fmaxf(v2 ? sv2 : NEG_INF, v3 ? sv3 : NEG_INF));
            tmax = fmaxf(tmax, __shfl_xor(tmax, 16));
            tmax = fmaxf(tmax, __shfl_xor(tmax, 32));
            const float m_new = fmaxf(m_run, tmax);
            const float fs = expf(m_run - m_new);    // 0 on first tile (m_run=-inf)
            const float w0 = v0 ? expf(sv0 - m_new) : 0.f;
            const float w1 = v1 ? expf(sv1 - m_new) : 0.f;
            const float w2 = v2 ? expf(sv2 - m_new) : 0.f;
            const float w3 = v3 ? expf(sv3 - m_new) : 0.f;
            float wsum = (w0 + w1) + (w2 + w3);
            float cp[4];
            #pragma unroll
            for (int nt = 0; nt < 4; ++nt)
                cp[nt] = ((w0*occ[nt][0] + w1*occ[nt][1]) + (w2*occ[nt][2] + w3*occ[nt][3]));
            wsum += __shfl_xor(wsum, 16); wsum += __shfl_xor(wsum, 32);
            #pragma unroll
            for (int nt = 0; nt < 4; ++nt){
                cp[nt] += __shfl_xor(cp[nt], 16);
                cp[nt] += __shfl_xor(cp[nt], 32);
            }
            run_sum = run_sum * fs + wsum;
            #pragma unroll
            for (int nt = 0; nt < 4; ++nt) outacc[nt] = outacc[nt] * fs + cp[nt];
            m_run = m_new;
        }

        const float inv = 1.f / run_sum;
        if (kg == 0){
            #pragma unroll
            for (int nt = 0; nt < 4; ++nt)
                out[(long)n * 64 + 16*nt + nidx] = outacc[nt] * inv;
        }
    }
    #undef BF
}

extern "C" void kernel_launch(void* const* d_in, const int* in_sizes, int n_in,
                              void* d_out, int out_size, void* d_ws, size_t ws_size,
                              hipStream_t stream) {
    const int*   nodes  = (const int*)d_in[0];
    const int*   hitems = (const int*)d_in[1];
    const int*   hrat   = (const int*)d_in[2];
    const int*   hlenp  = (const int*)d_in[3];
    const float* u2e    = (const float*)d_in[4];
    const float* i2e    = (const float*)d_in[5];
    const float* r2e    = (const float*)d_in[6];
    const float* w1w    = (const float*)d_in[7];
    const float* w1b    = (const float*)d_in[8];
    const float* w2w    = (const float*)d_in[9];
    const float* w2b    = (const float*)d_in[10];
    const float* a1w    = (const float*)d_in[11];
    const float* a1b    = (const float*)d_in[12];
    const float* a2w    = (const float*)d_in[13];
    const float* a2b    = (const float*)d_in[14];
    const float* a3w    = (const float*)d_in[15];
    const float* a3b    = (const float*)d_in[16];
    float* out = (float*)d_out;

    const int n_nodes = in_sizes[0];
    const int blocks  = 512;   // 2 blocks/CU resident for the whole kernel; 4 nodes per wave
    ue_v7<<<dim3(blocks), dim3(512), 0, stream>>>(
        nodes, hitems, hrat, hlenp, u2e, i2e, r2e,
        w1w, w1b, w2w, w2b, a1w, a1b, a2w, a2b, a3w, a3b,
        out, n_nodes);
}

// Round 22
// 110.671 us; speedup vs baseline: 2.5436x; 1.3074x over previous
//
#include <hip/hip_runtime.h>
#include <hip/hip_fp16.h>

#define HIST 50
#define WPB 8   // waves per block (512 threads)

typedef __fp16 hf;
typedef __fp16 hf2 __attribute__((ext_vector_type(2)));
typedef __fp16 h8  __attribute__((ext_vector_type(8)));
typedef float  f4  __attribute__((ext_vector_type(4)));

union U32H2 { unsigned u; hf2 h; };
__device__ __forceinline__ unsigned h2u(hf2 h){ U32H2 c; c.h=h; return c.u; }
__device__ __forceinline__ hf2 pkrtz(float a,float b){ return __builtin_amdgcn_cvt_pkrtz(a,b); }

__device__ __forceinline__ h8 mk8(hf2 a, hf2 b, hf2 c, hf2 d){
    h8 r; r[0]=a[0]; r[1]=a[1]; r[2]=b[0]; r[3]=b[1]; r[4]=c[0]; r[5]=c[1]; r[6]=d[0]; r[7]=d[1]; return r;
}
// 8 consecutive f32 at W[row + kb .. +7] -> f16x8 fragment
__device__ __forceinline__ h8 ldfrag(const float* W, long row, int kb){
    const float4 v0 = *(const float4*)(W + row + kb);
    const float4 v1 = *(const float4*)(W + row + kb + 4);
    return mk8(pkrtz(v0.x,v0.y), pkrtz(v0.z,v0.w), pkrtz(v1.x,v1.y), pkrtz(v1.z,v1.w));
}
__device__ __forceinline__ f4 mfma16(h8 a, h8 b, f4 c){
    return __builtin_amdgcn_mfma_f32_16x16x32_f16(a,b,c,0,0,0);
}
__device__ __forceinline__ f4 relu4(f4 v){
    v[0]=fmaxf(v[0],0.f); v[1]=fmaxf(v[1],0.f); v[2]=fmaxf(v[2],0.f); v[3]=fmaxf(v[3],0.f); return v;
}
// intra-wave LDS write->read fence (in-order DS pipe + stop compiler reordering; rule #18)
__device__ __forceinline__ void wsync(){
    asm volatile("s_waitcnt lgkmcnt(0)" ::: "memory");
    __builtin_amdgcn_sched_barrier(0);
}

// store C-layout tile (acc[nt]: col=16nt+(lane&15), rows (lane>>4)*4+r) as swizzled f16 [16][64]
// SHUFFLE-FREE: each lane owns one column -> 16 direct ds_write_b16 at swizzled addresses.
// Same layout as read_af below (gp = (c>>3)^(m&7); byte = m*128 + gp*16 + (2c&15)).
__device__ __forceinline__ void store_ct(unsigned short* base, const f4* acc, int lane){
    const int m0 = (lane >> 4) * 4;
    const int ci = lane & 15;
    #pragma unroll
    for (int nt = 0; nt < 4; ++nt){
        const int c = 16*nt + ci;
        #pragma unroll
        for (int r = 0; r < 4; ++r){
            const int m    = m0 + r;
            const int gp   = (c >> 3) ^ (m & 7);
            const int byte = m*128 + gp*16 + ((2*c) & 15);
            *(hf*)((char*)base + byte) = (hf)acc[nt][r];   // RNE f32->f16
        }
    }
}
__device__ __forceinline__ h8 read_af(const unsigned short* base, int lane, int kt){
    const int row  = lane & 15;
    const int gp   = (4*kt + (lane>>4)) ^ (row & 7);
    const int byte = row*128 + gp*16;
    return *(const h8*)((const char*)base + byte);
}

__global__ __launch_bounds__(512, 2)   // verified no-spill operating point (VGPR ~108)
void ue_v8(const int* __restrict__ nodes, const int* __restrict__ hitems,
           const int* __restrict__ hrat, const int* __restrict__ hlen,
           const float* __restrict__ u2e, const float* __restrict__ i2e,
           const float* __restrict__ r2e,
           const float* __restrict__ w1w, const float* __restrict__ w1b,
           const float* __restrict__ w2w, const float* __restrict__ w2b,
           const float* __restrict__ a1w, const float* __restrict__ a1b,
           const float* __restrict__ a2w, const float* __restrict__ a2b,
           const float* __restrict__ a3w, const float* __restrict__ a3b,
           float* __restrict__ out, int n_nodes)
{
    const int tid  = threadIdx.x;
    const int lane = tid & 63;
    const int wid  = tid >> 6;
    const int nidx = lane & 15;
    const int kg   = lane >> 4;

    // weight fragments: 40 blocks (W1:0-15, W2:16-23, A1o:24-31, A2:32-39), each 64 lanes x 16B
    __shared__ __align__(16) unsigned short wlds[40*512];
    __shared__ __align__(16) unsigned short xfer[WPB][16*64];   // per-wave transpose buffer
    __shared__ __align__(16) float uax[WPB][64];
    __shared__ __align__(16) float ubl[WPB][64];
    __shared__ int ihs[WPB][HIST];
    __shared__ int rhs[WPB][HIST];

    // ---- cooperative weight staging (once per persistent block) ----
    for (int f = tid; f < 40*64; f += blockDim.x) {
        const int blk = f >> 6, l = f & 63;
        const float* src; int ld, kt, nt;
        if (blk < 16)      { kt = blk>>2;      nt = blk&3;      src = w1w; ld = 128; }
        else if (blk < 24) { kt = (blk-16)>>2; nt = (blk-16)&3; src = w2w; ld = 64;  }
        else if (blk < 32) { kt = (blk-24)>>2; nt = (blk-24)&3; src = a1w; ld = 128; }
        else               { kt = (blk-32)>>2; nt = (blk-32)&3; src = a2w; ld = 64;  }
        const int nrow = 16*nt + (l & 15);
        const int kcol = 32*kt + 8*(l >> 4);
        *(h8*)&wlds[blk*512 + l*8] = ldfrag(src, (long)nrow*ld, kcol);
    }
    __syncthreads();   // the ONLY block-wide barrier

    #define BF(base,kt,nt) (*(const h8*)&wlds[((base)+(kt)*4+(nt))*512 + lane*8])

    float b1c[4], b2c[4], ab2c[4], a3c[4];
    #pragma unroll
    for (int nt = 0; nt < 4; ++nt){
        b1c[nt]  = w1b[16*nt + nidx];
        b2c[nt]  = w2b[16*nt + nidx];
        ab2c[nt] = a2b[16*nt + nidx];
        a3c[nt]  = a3w[16*nt + nidx];
    }
    const float ab1r = a1b[lane];
    const float NEG_INF = -__builtin_inff();

    // grid-stride: each wave handles ~4 nodes (sum of ragged hl -> better balance)
    for (int n = blockIdx.x * WPB + wid; n < n_nodes; n += gridDim.x * WPB) {
        const int node = nodes[n];
        const int hl   = hlen[n];

        uax[wid][lane] = u2e[(long)node * 64 + lane];
        if (lane < HIST){ ihs[wid][lane] = hitems[n*HIST+lane]; rhs[wid][lane] = hrat[n*HIST+lane]; }
        wsync();

        // ubias_j = ab1_j + sum_k u_k * A1[j][64+k]  (u-half of att1, folded per node)
        float u0 = ab1r, u1 = 0.f, u2 = 0.f, u3 = 0.f;
        #pragma unroll
        for (int t = 0; t < 16; ++t) {
            const float4 v = *(const float4*)(a1w + (long)lane*128 + 64 + 4*t);
            u0 = fmaf(v.x, uax[wid][4*t+0], u0);
            u1 = fmaf(v.y, uax[wid][4*t+1], u1);
            u2 = fmaf(v.z, uax[wid][4*t+2], u2);
            u3 = fmaf(v.w, uax[wid][4*t+3], u3);
        }
        ubl[wid][lane] = (u0 + u1) + (u2 + u3);
        wsync();
        float ubc[4];
        #pragma unroll
        for (int nt = 0; nt < 4; ++nt) ubc[nt] = ubl[wid][16*nt + nidx];

        // online softmax state
        float m_run = NEG_INF, run_sum = 0.f;
        float outacc[4] = {0.f, 0.f, 0.f, 0.f};

        const int tiles = (hl + 15) >> 4;
        for (int t = 0; t < tiles; ++t) {
            int p = t*16 + nidx; if (p >= hl) p = hl - 1;   // clamp pad rows (masked below)
            const long irow = (long)ihs[wid][p] * 64;
            const long rrow = (long)rhs[wid][p] * 64;
            const int  kb   = 8 * kg;
            const h8 Xf0 = ldfrag(i2e, irow, kb);
            const h8 Xf1 = ldfrag(i2e, irow, 32 + kb);
            const h8 Xf2 = ldfrag(r2e, rrow, kb);
            const h8 Xf3 = ldfrag(r2e, rrow, 32 + kb);

            // layer 1: [16x128] @ [128x64]
            f4 acc[4];
            #pragma unroll
            for (int nt = 0; nt < 4; ++nt){
                f4 c = { b1c[nt], b1c[nt], b1c[nt], b1c[nt] };
                c = mfma16(Xf0, BF(0,0,nt), c);
                c = mfma16(Xf1, BF(0,1,nt), c);
                c = mfma16(Xf2, BF(0,2,nt), c);
                c = mfma16(Xf3, BF(0,3,nt), c);
                acc[nt] = relu4(c);
            }
            store_ct(xfer[wid], acc, lane);
            wsync();
            const h8 yf0 = read_af(xfer[wid], lane, 0), yf1 = read_af(xfer[wid], lane, 1);

            // layer 2 -> o (stays in f32 C-layout regs)
            f4 occ[4];
            #pragma unroll
            for (int nt = 0; nt < 4; ++nt){
                f4 c = { b2c[nt], b2c[nt], b2c[nt], b2c[nt] };
                c = mfma16(yf0, BF(16,0,nt), c);
                c = mfma16(yf1, BF(16,1,nt), c);
                occ[nt] = relu4(c);
            }
            store_ct(xfer[wid], occ, lane);
            wsync();
            const h8 of0 = read_af(xfer[wid], lane, 0), of1 = read_af(xfer[wid], lane, 1);

            // att layer 1 (o-half; u folded in ubias)
            #pragma unroll
            for (int nt = 0; nt < 4; ++nt){
                f4 c = { ubc[nt], ubc[nt], ubc[nt], ubc[nt] };
                c = mfma16(of0, BF(24,0,nt), c);
                c = mfma16(of1, BF(24,1,nt), c);
                acc[nt] = relu4(c);
            }
            store_ct(xfer[wid], acc, lane);
            wsync();
            const h8 af0 = read_af(xfer[wid], lane, 0), af1 = read_af(xfer[wid], lane, 1);

            // att layer 2
            #pragma unroll
            for (int nt = 0; nt < 4; ++nt){
                f4 c = { ab2c[nt], ab2c[nt], ab2c[nt], ab2c[nt] };
                c = mfma16(af0, BF(32,0,nt), c);
                c = mfma16(af1, BF(32,1,nt), c);
                acc[nt] = relu4(c);
            }

            // scores per row (att3 bias dropped: softmax shift-invariant)
            float sv0 = 0.f, sv1 = 0.f, sv2 = 0.f, sv3 = 0.f;
            #pragma unroll
            for (int nt = 0; nt < 4; ++nt){
                sv0 = fmaf(acc[nt][0], a3c[nt], sv0);
                sv1 = fmaf(acc[nt][1], a3c[nt], sv1);
                sv2 = fmaf(acc[nt][2], a3c[nt], sv2);
                sv3 = fmaf(acc[nt][3], a3c[nt], sv3);
            }
            #pragma unroll
            for (int off = 1; off <= 8; off <<= 1){
                sv0 += __shfl_xor(sv0, off);
                sv1 += __shfl_xor(sv1, off);
                sv2 += __shfl_xor(sv2, off);
                sv3 += __shfl_xor(sv3, off);
            }

            // online softmax update over this tile's 16 rows
            const int base = t*16 + kg*4;
            const bool v0 = base+0 < hl, v1 = base+1 < hl, v2 = base+2 < hl, v3 = base+3 < hl;
            float tmax = fmaxf(fmaxf(v0 ? sv0 : NEG_INF, v1 ? sv1 : NEG_INF),
                               fmaxf(v2 ? sv2 : NEG_INF, v3 ? sv3 : NEG_INF));
            tmax = fmaxf(tmax, __shfl_xor(tmax, 16));
            tmax = fmaxf(tmax, __shfl_xor(tmax, 32));
            const float m_new = fmaxf(m_run, tmax);
            const float fs = expf(m_run - m_new);    // 0 on first tile (m_run=-inf)
            const float w0 = v0 ? expf(sv0 - m_new) : 0.f;
            const float w1 = v1 ? expf(sv1 - m_new) : 0.f;
            const float w2 = v2 ? expf(sv2 - m_new) : 0.f;
            const float w3 = v3 ? expf(sv3 - m_new) : 0.f;
            float wsum = (w0 + w1) + (w2 + w3);
            float cp[4];
            #pragma unroll
            for (int nt = 0; nt < 4; ++nt)
                cp[nt] = ((w0*occ[nt][0] + w1*occ[nt][1]) + (w2*occ[nt][2] + w3*occ[nt][3]));
            wsum += __shfl_xor(wsum, 16); wsum += __shfl_xor(wsum, 32);
            #pragma unroll
            for (int nt = 0; nt < 4; ++nt){
                cp[nt] += __shfl_xor(cp[nt], 16);
                cp[nt] += __shfl_xor(cp[nt], 32);
            }
            run_sum = run_sum * fs + wsum;
            #pragma unroll
            for (int nt = 0; nt < 4; ++nt) outacc[nt] = outacc[nt] * fs + cp[nt];
            m_run = m_new;
        }

        const float inv = 1.f / run_sum;
        if (kg == 0){
            #pragma unroll
            for (int nt = 0; nt < 4; ++nt)
                out[(long)n * 64 + 16*nt + nidx] = outacc[nt] * inv;
        }
    }
    #undef BF
}

extern "C" void kernel_launch(void* const* d_in, const int* in_sizes, int n_in,
                              void* d_out, int out_size, void* d_ws, size_t ws_size,
                              hipStream_t stream) {
    const int*   nodes  = (const int*)d_in[0];
    const int*   hitems = (const int*)d_in[1];
    const int*   hrat   = (const int*)d_in[2];
    const int*   hlenp  = (const int*)d_in[3];
    const float* u2e    = (const float*)d_in[4];
    const float* i2e    = (const float*)d_in[5];
    const float* r2e    = (const float*)d_in[6];
    const float* w1w    = (const float*)d_in[7];
    const float* w1b    = (const float*)d_in[8];
    const float* w2w    = (const float*)d_in[9];
    const float* w2b    = (const float*)d_in[10];
    const float* a1w    = (const float*)d_in[11];
    const float* a1b    = (const float*)d_in[12];
    const float* a2w    = (const float*)d_in[13];
    const float* a2b    = (const float*)d_in[14];
    const float* a3w    = (const float*)d_in[15];
    const float* a3b    = (const float*)d_in[16];
    float* out = (float*)d_out;

    const int n_nodes = in_sizes[0];
    const int blocks  = 512;   // persistent: 2 blocks/CU resident, ~4 nodes per wave
    ue_v8<<<dim3(blocks), dim3(512), 0, stream>>>(
        nodes, hitems, hrat, hlenp, u2e, i2e, r2e,
        w1w, w1b, w2w, w2b, a1w, a1b, a2w, a2b, a3w, a3b,
        out, n_nodes);
}

// Round 23
// 100.116 us; speedup vs baseline: 2.8117x; 1.1054x over previous
//
#include <hip/hip_runtime.h>
#include <hip/hip_fp16.h>

#define HIST 50
#define WPB 4   // waves per block (256 threads); LDS-limited with 32-pair xfer

typedef __fp16 hf;
typedef __fp16 hf2 __attribute__((ext_vector_type(2)));
typedef __fp16 h8  __attribute__((ext_vector_type(8)));
typedef float  f4  __attribute__((ext_vector_type(4)));

union U32H2 { unsigned u; hf2 h; };
__device__ __forceinline__ unsigned h2u(hf2 h){ U32H2 c; c.h=h; return c.u; }
__device__ __forceinline__ hf2 pkrtz(float a,float b){ return __builtin_amdgcn_cvt_pkrtz(a,b); }

__device__ __forceinline__ h8 mk8(hf2 a, hf2 b, hf2 c, hf2 d){
    h8 r; r[0]=a[0]; r[1]=a[1]; r[2]=b[0]; r[3]=b[1]; r[4]=c[0]; r[5]=c[1]; r[6]=d[0]; r[7]=d[1]; return r;
}
// 8 consecutive f32 at W[row + kb .. +7] -> f16x8 fragment
__device__ __forceinline__ h8 ldfrag(const float* W, long row, int kb){
    const float4 v0 = *(const float4*)(W + row + kb);
    const float4 v1 = *(const float4*)(W + row + kb + 4);
    return mk8(pkrtz(v0.x,v0.y), pkrtz(v0.z,v0.w), pkrtz(v1.x,v1.y), pkrtz(v1.z,v1.w));
}
__device__ __forceinline__ f4 mfma16(h8 a, h8 b, f4 c){
    return __builtin_amdgcn_mfma_f32_16x16x32_f16(a,b,c,0,0,0);
}
__device__ __forceinline__ f4 relu4(f4 v){
    v[0]=fmaxf(v[0],0.f); v[1]=fmaxf(v[1],0.f); v[2]=fmaxf(v[2],0.f); v[3]=fmaxf(v[3],0.f); return v;
}
// intra-wave LDS write->read fence (rule #18)
__device__ __forceinline__ void wsync(){
    asm volatile("s_waitcnt lgkmcnt(0)" ::: "memory");
    __builtin_amdgcn_sched_barrier(0);
}

// store C-layout sub-tile (pairs pt*16+4kg+r rows, feat col 16nt+nidx) into swizzled f16 [32][64]
__device__ __forceinline__ void store_ct(unsigned short* base, const f4* acc, int lane, int pt){
    const int m0 = pt*16 + (lane >> 4) * 4;
    const int ci = lane & 15;
    #pragma unroll
    for (int nt = 0; nt < 4; ++nt){
        const int c = 16*nt + ci;
        #pragma unroll
        for (int r = 0; r < 4; ++r){
            const int m    = m0 + r;
            const int gp   = (c >> 3) ^ (m & 7);
            const int byte = m*128 + gp*16 + ((2*c) & 15);
            *(hf*)((char*)base + byte) = (hf)acc[nt][r];   // RNE f32->f16
        }
    }
}
// read A-fragment (row = pt*16 + (lane&15), k = 32kt+8*(lane>>4)+i) from swizzled [32][64]
__device__ __forceinline__ h8 read_af(const unsigned short* base, int lane, int kt, int pt){
    const int row  = pt*16 + (lane & 15);
    const int gp   = (4*kt + (lane>>4)) ^ (row & 7);
    const int byte = row*128 + gp*16;
    return *(const h8*)((const char*)base + byte);
}

__global__ __launch_bounds__(256, 2)   // 256-VGPR budget (no-spill envelope)
void ue_v9(const int* __restrict__ nodes, const int* __restrict__ hitems,
           const int* __restrict__ hrat, const int* __restrict__ hlen,
           const float* __restrict__ u2e, const float* __restrict__ i2e,
           const float* __restrict__ r2e,
           const float* __restrict__ w1w, const float* __restrict__ w1b,
           const float* __restrict__ w2w, const float* __restrict__ w2b,
           const float* __restrict__ a1w, const float* __restrict__ a1b,
           const float* __restrict__ a2w, const float* __restrict__ a2b,
           const float* __restrict__ a3w, const float* __restrict__ a3b,
           float* __restrict__ out, int n_nodes)
{
    const int tid  = threadIdx.x;
    const int lane = tid & 63;
    const int wid  = tid >> 6;
    const int nidx = lane & 15;
    const int kg   = lane >> 4;

    // weight fragments: 40 blocks (W1:0-15, W2:16-23, A1o:24-31, A2:32-39), each 1 KB
    __shared__ __align__(16) unsigned short wlds[40*512];
    __shared__ __align__(16) unsigned short xfer[WPB][32*64];   // per-wave transpose buffer (32 pairs)
    __shared__ __align__(16) float uax[WPB][64];
    __shared__ __align__(16) float ubl[WPB][64];
    __shared__ int ihs[WPB][HIST];
    __shared__ int rhs[WPB][HIST];

    // ---- cooperative weight staging (once per persistent block) ----
    for (int f = tid; f < 40*64; f += blockDim.x) {
        const int blk = f >> 6, l = f & 63;
        const float* src; int ld, kt, nt;
        if (blk < 16)      { kt = blk>>2;      nt = blk&3;      src = w1w; ld = 128; }
        else if (blk < 24) { kt = (blk-16)>>2; nt = (blk-16)&3; src = w2w; ld = 64;  }
        else if (blk < 32) { kt = (blk-24)>>2; nt = (blk-24)&3; src = a1w; ld = 128; }
        else               { kt = (blk-32)>>2; nt = (blk-32)&3; src = a2w; ld = 64;  }
        const int nrow = 16*nt + (l & 15);
        const int kcol = 32*kt + 8*(l >> 4);
        *(h8*)&wlds[blk*512 + l*8] = ldfrag(src, (long)nrow*ld, kcol);
    }
    __syncthreads();   // the ONLY block-wide barrier

    #define BF(base,kt,nt) (*(const h8*)&wlds[((base)+(kt)*4+(nt))*512 + lane*8])

    float b1c[4], b2c[4], ab2c[4], a3c[4];
    #pragma unroll
    for (int nt = 0; nt < 4; ++nt){
        b1c[nt]  = w1b[16*nt + nidx];
        b2c[nt]  = w2b[16*nt + nidx];
        ab2c[nt] = a2b[16*nt + nidx];
        a3c[nt]  = a3w[16*nt + nidx];
    }
    const float ab1r = a1b[lane];
    const float NEG_INF = -__builtin_inff();

    // grid-stride: each wave handles ~8 nodes (sum of ragged hl -> good balance)
    for (int n = blockIdx.x * WPB + wid; n < n_nodes; n += gridDim.x * WPB) {
        const int node = nodes[n];
        const int hl   = hlen[n];

        uax[wid][lane] = u2e[(long)node * 64 + lane];
        if (lane < HIST){ ihs[wid][lane] = hitems[n*HIST+lane]; rhs[wid][lane] = hrat[n*HIST+lane]; }
        wsync();

        // ubias_j = ab1_j + sum_k u_k * A1[j][64+k]
        float u0 = ab1r, u1 = 0.f, u2 = 0.f, u3 = 0.f;
        #pragma unroll
        for (int t = 0; t < 16; ++t) {
            const float4 v = *(const float4*)(a1w + (long)lane*128 + 64 + 4*t);
            u0 = fmaf(v.x, uax[wid][4*t+0], u0);
            u1 = fmaf(v.y, uax[wid][4*t+1], u1);
            u2 = fmaf(v.z, uax[wid][4*t+2], u2);
            u3 = fmaf(v.w, uax[wid][4*t+3], u3);
        }
        ubl[wid][lane] = (u0 + u1) + (u2 + u3);
        wsync();
        float ubc[4];
        #pragma unroll
        for (int nt = 0; nt < 4; ++nt) ubc[nt] = ubl[wid][16*nt + nidx];

        // online softmax state
        float m_run = NEG_INF, run_sum = 0.f;
        float outacc[4] = {0.f, 0.f, 0.f, 0.f};

        const int tiles = (hl + 31) >> 5;   // 32 pairs per tile
        for (int t = 0; t < tiles; ++t) {
            // ---- X fragments for both 16-pair sub-tiles ----
            h8 Xf[2][4];
            #pragma unroll
            for (int pt = 0; pt < 2; ++pt){
                int p = t*32 + pt*16 + nidx; if (p >= hl) p = hl - 1;
                const long irow = (long)ihs[wid][p] * 64;
                const long rrow = (long)rhs[wid][p] * 64;
                const int  kb   = 8 * kg;
                Xf[pt][0] = ldfrag(i2e, irow, kb);
                Xf[pt][1] = ldfrag(i2e, irow, 32 + kb);
                Xf[pt][2] = ldfrag(r2e, rrow, kb);
                Xf[pt][3] = ldfrag(r2e, rrow, 32 + kb);
            }

            // ---- layer 1: [32x128] @ [128x64] ----
            #pragma unroll
            for (int pt = 0; pt < 2; ++pt){
                f4 acc[4];
                #pragma unroll
                for (int nt = 0; nt < 4; ++nt){
                    f4 c = { b1c[nt], b1c[nt], b1c[nt], b1c[nt] };
                    c = mfma16(Xf[pt][0], BF(0,0,nt), c);
                    c = mfma16(Xf[pt][1], BF(0,1,nt), c);
                    c = mfma16(Xf[pt][2], BF(0,2,nt), c);
                    c = mfma16(Xf[pt][3], BF(0,3,nt), c);
                    acc[nt] = relu4(c);
                }
                store_ct(xfer[wid], acc, lane, pt);
            }
            wsync();

            // ---- layer 2 -> o (C-layout regs, both sub-tiles) ----
            f4 occ[2][4];
            #pragma unroll
            for (int pt = 0; pt < 2; ++pt){
                const h8 yf0 = read_af(xfer[wid], lane, 0, pt);
                const h8 yf1 = read_af(xfer[wid], lane, 1, pt);
                #pragma unroll
                for (int nt = 0; nt < 4; ++nt){
                    f4 c = { b2c[nt], b2c[nt], b2c[nt], b2c[nt] };
                    c = mfma16(yf0, BF(16,0,nt), c);
                    c = mfma16(yf1, BF(16,1,nt), c);
                    occ[pt][nt] = relu4(c);
                }
                store_ct(xfer[wid], occ[pt], lane, pt);
            }
            wsync();

            // ---- att layer 1 (o-half; u folded in ubias) ----
            #pragma unroll
            for (int pt = 0; pt < 2; ++pt){
                const h8 of0 = read_af(xfer[wid], lane, 0, pt);
                const h8 of1 = read_af(xfer[wid], lane, 1, pt);
                f4 acc[4];
                #pragma unroll
                for (int nt = 0; nt < 4; ++nt){
                    f4 c = { ubc[nt], ubc[nt], ubc[nt], ubc[nt] };
                    c = mfma16(of0, BF(24,0,nt), c);
                    c = mfma16(of1, BF(24,1,nt), c);
                    acc[nt] = relu4(c);
                }
                store_ct(xfer[wid], acc, lane, pt);
            }
            wsync();

            // ---- att layer 2 + scores + online softmax for 8 pairs/lane ----
            float w8[2][4];
            float tmax = NEG_INF;
            #pragma unroll
            for (int pt = 0; pt < 2; ++pt){
                const h8 af0 = read_af(xfer[wid], lane, 0, pt);
                const h8 af1 = read_af(xfer[wid], lane, 1, pt);
                f4 acc[4];
                #pragma unroll
                for (int nt = 0; nt < 4; ++nt){
                    f4 c = { ab2c[nt], ab2c[nt], ab2c[nt], ab2c[nt] };
                    c = mfma16(af0, BF(32,0,nt), c);
                    c = mfma16(af1, BF(32,1,nt), c);
                    acc[nt] = relu4(c);
                }
                float sv0 = 0.f, sv1 = 0.f, sv2 = 0.f, sv3 = 0.f;
                #pragma unroll
                for (int nt = 0; nt < 4; ++nt){
                    sv0 = fmaf(acc[nt][0], a3c[nt], sv0);
                    sv1 = fmaf(acc[nt][1], a3c[nt], sv1);
                    sv2 = fmaf(acc[nt][2], a3c[nt], sv2);
                    sv3 = fmaf(acc[nt][3], a3c[nt], sv3);
                }
                #pragma unroll
                for (int off = 1; off <= 8; off <<= 1){
                    sv0 += __shfl_xor(sv0, off);
                    sv1 += __shfl_xor(sv1, off);
                    sv2 += __shfl_xor(sv2, off);
                    sv3 += __shfl_xor(sv3, off);
                }
                const int base = t*32 + pt*16 + kg*4;
                w8[pt][0] = (base+0 < hl) ? sv0 : NEG_INF;
                w8[pt][1] = (base+1 < hl) ? sv1 : NEG_INF;
                w8[pt][2] = (base+2 < hl) ? sv2 : NEG_INF;
                w8[pt][3] = (base+3 < hl) ? sv3 : NEG_INF;
                tmax = fmaxf(tmax, fmaxf(fmaxf(w8[pt][0], w8[pt][1]), fmaxf(w8[pt][2], w8[pt][3])));
            }
            tmax = fmaxf(tmax, __shfl_xor(tmax, 16));
            tmax = fmaxf(tmax, __shfl_xor(tmax, 32));
            const float m_new = fmaxf(m_run, tmax);
            const float fs = expf(m_run - m_new);    // 0 on first tile
            float wsum = 0.f;
            #pragma unroll
            for (int pt = 0; pt < 2; ++pt)
                #pragma unroll
                for (int r = 0; r < 4; ++r){
                    w8[pt][r] = (w8[pt][r] == NEG_INF) ? 0.f : expf(w8[pt][r] - m_new);
                    wsum += w8[pt][r];
                }
            float cp[4];
            #pragma unroll
            for (int nt = 0; nt < 4; ++nt){
                cp[nt] = ((w8[0][0]*occ[0][nt][0] + w8[0][1]*occ[0][nt][1]) +
                          (w8[0][2]*occ[0][nt][2] + w8[0][3]*occ[0][nt][3])) +
                         ((w8[1][0]*occ[1][nt][0] + w8[1][1]*occ[1][nt][1]) +
                          (w8[1][2]*occ[1][nt][2] + w8[1][3]*occ[1][nt][3]));
            }
            wsum += __shfl_xor(wsum, 16); wsum += __shfl_xor(wsum, 32);
            #pragma unroll
            for (int nt = 0; nt < 4; ++nt){
                cp[nt] += __shfl_xor(cp[nt], 16);
                cp[nt] += __shfl_xor(cp[nt], 32);
            }
            run_sum = run_sum * fs + wsum;
            #pragma unroll
            for (int nt = 0; nt < 4; ++nt) outacc[nt] = outacc[nt] * fs + cp[nt];
            m_run = m_new;
        }

        const float inv = 1.f / run_sum;
        if (kg == 0){
            #pragma unroll
            for (int nt = 0; nt < 4; ++nt)
                out[(long)n * 64 + 16*nt + nidx] = outacc[nt] * inv;
        }
    }
    #undef BF
}

extern "C" void kernel_launch(void* const* d_in, const int* in_sizes, int n_in,
                              void* d_out, int out_size, void* d_ws, size_t ws_size,
                              hipStream_t stream) {
    const int*   nodes  = (const int*)d_in[0];
    const int*   hitems = (const int*)d_in[1];
    const int*   hrat   = (const int*)d_in[2];
    const int*   hlenp  = (const int*)d_in[3];
    const float* u2e    = (const float*)d_in[4];
    const float* i2e    = (const float*)d_in[5];
    const float* r2e    = (const float*)d_in[6];
    const float* w1w    = (const float*)d_in[7];
    const float* w1b    = (const float*)d_in[8];
    const float* w2w    = (const float*)d_in[9];
    const float* w2b    = (const float*)d_in[10];
    const float* a1w    = (const float*)d_in[11];
    const float* a1b    = (const float*)d_in[12];
    const float* a2w    = (const float*)d_in[13];
    const float* a2b    = (const float*)d_in[14];
    const float* a3w    = (const float*)d_in[15];
    const float* a3b    = (const float*)d_in[16];
    float* out = (float*)d_out;

    const int n_nodes = in_sizes[0];
    const int blocks  = 512;   // persistent: 2 blocks/CU (61 KB LDS), 4 waves each, ~8 nodes/wave
    ue_v9<<<dim3(blocks), dim3(256), 0, stream>>>(
        nodes, hitems, hrat, hlenp, u2e, i2e, r2e,
        w1w, w1b, w2w, w2b, a1w, a1b, a2w, a2b, a3w, a3b,
        out, n_nodes);
}